// Round 1
// baseline (514.312 us; speedup 1.0000x reference)
//
#include <hip/hip_runtime.h>
#include <math.h>

// Problem constants
#define B 128
#define T 1024
#define H 512
#define L 2
#define G3H 1536   // 3*H

// ---------------------------------------------------------------------------
// Kernel 1: score[b,t] = dot(enc[b,t,:], w_e)
// (hidden@w_h and attn_b cancel under softmax -> skipped)
// grid 8192 x 256 threads; each wave handles 4 consecutive (b,t) rows.
__global__ void score_kernel(const float* __restrict__ enc,
                             const float* __restrict__ attn_w,
                             float* __restrict__ score) {
    int tid  = threadIdx.x;
    int lane = tid & 63;
    int wave = tid >> 6;
    int gw = blockIdx.x * 4 + wave;              // 0..32767
    // w_e = attn_w[L*H ..], lane's 8 coefficients in registers
    const float4 we0 = *(const float4*)(attn_w + L * H + lane * 8);
    const float4 we1 = *(const float4*)(attn_w + L * H + lane * 8 + 4);
    size_t base = (size_t)gw * 4 * H + lane * 8;
#pragma unroll
    for (int i = 0; i < 4; i++) {
        const float4 e0 = *(const float4*)(enc + base + (size_t)i * H);
        const float4 e1 = *(const float4*)(enc + base + (size_t)i * H + 4);
        float d = e0.x * we0.x + e0.y * we0.y + e0.z * we0.z + e0.w * we0.w
                + e1.x * we1.x + e1.y * we1.y + e1.z * we1.z + e1.w * we1.w;
#pragma unroll
        for (int off = 32; off; off >>= 1) d += __shfl_xor(d, off);
        if (lane == 0) score[gw * 4 + i] = d;     // layout b*T + t
    }
}

// ---------------------------------------------------------------------------
// Kernel 2: softmax over t per b. grid 128 x 256; thread owns 4 t's (float4).
__global__ void softmax_kernel(const float* __restrict__ score,
                               float* __restrict__ attnw) {
    int b = blockIdx.x, tid = threadIdx.x;
    int lane = tid & 63, wave = tid >> 6;
    __shared__ float red[8];
    float4 v = *(const float4*)(score + b * T + tid * 4);
    float m = fmaxf(fmaxf(v.x, v.y), fmaxf(v.z, v.w));
#pragma unroll
    for (int off = 32; off; off >>= 1) m = fmaxf(m, __shfl_xor(m, off));
    if (lane == 0) red[wave] = m;
    __syncthreads();
    float M = fmaxf(fmaxf(red[0], red[1]), fmaxf(red[2], red[3]));
    float e0 = expf(v.x - M), e1 = expf(v.y - M);
    float e2 = expf(v.z - M), e3 = expf(v.w - M);
    float s = e0 + e1 + e2 + e3;
#pragma unroll
    for (int off = 32; off; off >>= 1) s += __shfl_xor(s, off);
    __syncthreads();
    if (lane == 0) red[4 + wave] = s;
    __syncthreads();
    float inv = 1.0f / (red[4] + red[5] + red[6] + red[7]);
    float4 o = {e0 * inv, e1 * inv, e2 * inv, e3 * inv};
    *(float4*)(attnw + b * T + tid * 4) = o;
}

// ---------------------------------------------------------------------------
// Kernel 3: partial attn_applied over a T-chunk of 256.
// grid (4, 128) x 256 threads; thread owns h=2*tid, 2*tid+1.
__global__ void attn_partial_kernel(const float* __restrict__ enc,
                                    const float* __restrict__ attnw,
                                    float* __restrict__ part) {
    int tc = blockIdx.x, b = blockIdx.y, tid = threadIdx.x;
    __shared__ float wl[256];
    wl[tid] = attnw[b * T + tc * 256 + tid];
    __syncthreads();
    const float* ep = enc + ((size_t)b * T + tc * 256) * H + tid * 2;
    float2 acc = {0.0f, 0.0f};
#pragma unroll 4
    for (int t = 0; t < 256; t++) {
        float2 e = *(const float2*)(ep + (size_t)t * H);
        float w = wl[t];
        acc.x += w * e.x;
        acc.y += w * e.y;
    }
    *(float2*)(part + ((size_t)tc * B + b) * H + tid * 2) = acc;
}

// ---------------------------------------------------------------------------
// Kernel 4: x[b,h] = relu(in0[b]*comb_w[h,0] + sum_j attn[b,j]*comb_w[h,1+j] + comb_b[h])
// grid (4, 128) x 256; block = (h-quarter q, batch b); wave-per-row dots.
__global__ void comb_kernel(const float* __restrict__ part,
                            const float* __restrict__ input,
                            const float* __restrict__ comb_w,
                            const float* __restrict__ comb_b,
                            float* __restrict__ x_out) {
    int q = blockIdx.x, b = blockIdx.y, tid = threadIdx.x;
    __shared__ float at[H];
    __shared__ float in0s;
    for (int j = tid; j < H; j += 256) {
        at[j] = part[(size_t)b * H + j]
              + part[(size_t)(B * H) + b * H + j]
              + part[(size_t)(2 * B * H) + b * H + j]
              + part[(size_t)(3 * B * H) + b * H + j];
    }
    if (tid == 0) in0s = input[b * 8 + 7];   // input[:, -1]
    __syncthreads();
    int lane = tid & 63, wave = tid >> 6;
    float in0 = in0s;
    float areg[8];
#pragma unroll
    for (int j = 0; j < 8; j++) areg[j] = at[j * 64 + lane];  // conflict-free
    for (int r = 0; r < 32; r++) {
        int h = q * 128 + wave * 32 + r;
        const float* wr = comb_w + (size_t)h * (H + 1);
        float d = 0.0f;
#pragma unroll
        for (int j = 0; j < 8; j++) d += areg[j] * wr[1 + j * 64 + lane];
#pragma unroll
        for (int off = 32; off; off >>= 1) d += __shfl_xor(d, off);
        if (lane == 0)
            x_out[(size_t)b * H + h] = fmaxf(0.0f, d + in0 * wr[0] + comb_b[h]);
    }
}

// ---------------------------------------------------------------------------
// Kernel 5: C = A @ W^T.  A:(B x H), W:(3H x H), C:(B x 3H).
// grid (48, 4, 2): x=n-tile, y=m-tile, z selects (x,w_ih,gx) vs (hidden,w_hh,gh).
__global__ void gemm_kernel(const float* __restrict__ A0,
                            const float* __restrict__ A1,
                            const float* __restrict__ W0,
                            const float* __restrict__ W1,
                            float* __restrict__ C0,
                            float* __restrict__ C1) {
    int z = blockIdx.z;
    const float* A = z ? A1 : A0;
    const float* W = z ? W1 : W0;
    float* C = z ? C1 : C0;
    __shared__ float As[32][33];
    __shared__ float Ws[32][33];
    int n0 = blockIdx.x * 32, m0 = blockIdx.y * 32;
    int tid = threadIdx.x;
    int lrow = tid >> 3;            // 0..31
    int lcol = (tid & 7) * 4;       // 0,4,..,28
    int tm = (tid >> 4) * 2;        // 0..30 even
    int tn = (tid & 15) * 2;
    float a00 = 0, a01 = 0, a10 = 0, a11 = 0;
    for (int k0 = 0; k0 < H; k0 += 32) {
        float4 av = *(const float4*)(A + (size_t)(m0 + lrow) * H + k0 + lcol);
        float4 wv = *(const float4*)(W + (size_t)(n0 + lrow) * H + k0 + lcol);
        __syncthreads();
        As[lrow][lcol] = av.x; As[lrow][lcol + 1] = av.y;
        As[lrow][lcol + 2] = av.z; As[lrow][lcol + 3] = av.w;
        Ws[lrow][lcol] = wv.x; Ws[lrow][lcol + 1] = wv.y;
        Ws[lrow][lcol + 2] = wv.z; Ws[lrow][lcol + 3] = wv.w;
        __syncthreads();
#pragma unroll
        for (int k = 0; k < 32; k++) {
            float x0 = As[tm][k], x1 = As[tm + 1][k];
            float w0 = Ws[tn][k], w1 = Ws[tn + 1][k];
            a00 += x0 * w0; a01 += x0 * w1;
            a10 += x1 * w0; a11 += x1 * w1;
        }
    }
    C[(size_t)(m0 + tm) * G3H + n0 + tn]         = a00;
    C[(size_t)(m0 + tm) * G3H + n0 + tn + 1]     = a01;
    C[(size_t)(m0 + tm + 1) * G3H + n0 + tn]     = a10;
    C[(size_t)(m0 + tm + 1) * G3H + n0 + tn + 1] = a11;
}

// ---------------------------------------------------------------------------
// Kernel 6: GRU gate combine. grid 256 x 256; one thread per (b,h).
__global__ void gates_kernel(const float* __restrict__ gx,
                             const float* __restrict__ gh,
                             const float* __restrict__ b_ih,
                             const float* __restrict__ b_hh,
                             const float* __restrict__ hprev,
                             float* __restrict__ hid_out,
                             float* __restrict__ x_out) {
    int idx = blockIdx.x * 256 + threadIdx.x;   // 0..65535
    int b = idx >> 9, h = idx & 511;
    size_t gb = (size_t)b * G3H;
    float xr = gx[gb + h]         + b_ih[h];
    float xz = gx[gb + H + h]     + b_ih[H + h];
    float xn = gx[gb + 2 * H + h] + b_ih[2 * H + h];
    float hr = gh[gb + h]         + b_hh[h];
    float hz = gh[gb + H + h]     + b_hh[H + h];
    float hn = gh[gb + 2 * H + h] + b_hh[2 * H + h];
    float hp = hprev[(size_t)b * H + h];
    float r = 1.0f / (1.0f + expf(-(xr + hr)));
    float z = 1.0f / (1.0f + expf(-(xz + hz)));
    float n = tanhf(xn + r * hn);
    float hnew = (1.0f - z) * n + z * hp;
    hid_out[(size_t)b * H + h] = hnew;
    x_out[(size_t)b * H + h] = hnew;
}

// ---------------------------------------------------------------------------
// Kernel 7: output[b] = dot(x[b], out_w) + out_b. grid 128 x 64.
__global__ void out_kernel(const float* __restrict__ x,
                           const float* __restrict__ out_w,
                           const float* __restrict__ out_b,
                           float* __restrict__ out) {
    int b = blockIdx.x, lane = threadIdx.x;
    const float4 w0 = *(const float4*)(out_w + lane * 8);
    const float4 w1 = *(const float4*)(out_w + lane * 8 + 4);
    const float4 x0 = *(const float4*)(x + (size_t)b * H + lane * 8);
    const float4 x1 = *(const float4*)(x + (size_t)b * H + lane * 8 + 4);
    float d = x0.x * w0.x + x0.y * w0.y + x0.z * w0.z + x0.w * w0.w
            + x1.x * w1.x + x1.y * w1.y + x1.z * w1.z + x1.w * w1.w;
#pragma unroll
    for (int off = 32; off; off >>= 1) d += __shfl_xor(d, off);
    if (lane == 0) out[b] = d + out_b[0];
}

// ---------------------------------------------------------------------------
extern "C" void kernel_launch(void* const* d_in, const int* in_sizes, int n_in,
                              void* d_out, int out_size, void* d_ws, size_t ws_size,
                              hipStream_t stream) {
    const float* input  = (const float*)d_in[0];
    const float* hidden = (const float*)d_in[1];
    const float* enc    = (const float*)d_in[2];
    const float* attn_w = (const float*)d_in[3];
    // d_in[4] = attn_b: cancels under softmax
    const float* comb_w = (const float*)d_in[5];
    const float* comb_b = (const float*)d_in[6];
    const float* w_ih   = (const float*)d_in[7];
    const float* w_hh   = (const float*)d_in[8];
    const float* b_ih   = (const float*)d_in[9];
    const float* b_hh   = (const float*)d_in[10];
    const float* out_w  = (const float*)d_in[11];
    const float* out_b  = (const float*)d_in[12];

    float* out = (float*)d_out;
    // d_out layout: output[128] | hidden_out[L*B*H] | attn_weights[B*T]
    float* hid_out = out + B;
    float* attnw   = out + B + L * B * H;

    float* ws    = (float*)d_ws;
    float* score = ws;                         // B*T       = 131072
    float* part  = score + B * T;              // 4*B*H     = 262144
    float* x     = part + 4 * B * H;           // B*H       = 65536
    float* gx    = x + B * H;                  // B*3H      = 196608
    float* gh    = gx + B * G3H;               // B*3H      = 196608

    score_kernel<<<dim3((B * T) / 16), 256, 0, stream>>>(enc, attn_w, score);
    softmax_kernel<<<dim3(B), 256, 0, stream>>>(score, attnw);
    attn_partial_kernel<<<dim3(4, B), 256, 0, stream>>>(enc, attnw, part);
    comb_kernel<<<dim3(4, B), 256, 0, stream>>>(part, input, comb_w, comb_b, x);

    for (int l = 0; l < L; l++) {
        const float* hl = hidden + (size_t)l * B * H;
        gemm_kernel<<<dim3(G3H / 32, B / 32, 2), 256, 0, stream>>>(
            x, hl,
            w_ih + (size_t)l * G3H * H, w_hh + (size_t)l * G3H * H,
            gx, gh);
        gates_kernel<<<dim3(B * H / 256), 256, 0, stream>>>(
            gx, gh, b_ih + l * G3H, b_hh + l * G3H, hl,
            hid_out + (size_t)l * B * H, x);
    }
    out_kernel<<<dim3(B), 64, 0, stream>>>(x, out_w, out_b, out);
}

// Round 2
// 458.485 us; speedup vs baseline: 1.1218x; 1.1218x over previous
//
#include <hip/hip_runtime.h>
#include <math.h>

// Problem constants
#define B 128
#define T 1024
#define H 512
#define L 2
#define G3H 1536   // 3*H
#define C 8        // attention T-chunks (grid.x)
#define TC 128     // T per chunk
#define TT 16      // t-tile staged in LDS
#define KS 4       // GEMM split-K factor

// ---------------------------------------------------------------------------
// Fused attention: score + online-softmax + weighted-sum in ONE enc pass.
// grid (C, B) x 256. Block (c,b) handles t in [c*TC, (c+1)*TC).
// Emits per-chunk partials: acc[512], (m,l) stats, and raw scores.
// hidden@w_h and attn_b are constant over t -> cancel under softmax.
__global__ __launch_bounds__(256, 4)
void attn_fused_kernel(const float* __restrict__ enc,
                       const float* __restrict__ attn_w,
                       float* __restrict__ score_out,
                       float* __restrict__ part,
                       float* __restrict__ stats) {
    int c = blockIdx.x, b = blockIdx.y;
    int tid = threadIdx.x, lane = tid & 63, wave = tid >> 6;
    __shared__ float tile[TT * H];     // 32 KB
    __shared__ float s_tile[TT];

    // w_e fragment: lane's j-th coeff at [lane + j*64] (stride-64, bank-free)
    float we[8];
#pragma unroll
    for (int j = 0; j < 8; j++) we[j] = attn_w[L * H + lane + j * 64];

    float m_run = -1e30f, l_run = 0.0f;
    float accx = 0.0f, accy = 0.0f;
    const float* encb = enc + ((size_t)b * T + c * TC) * H;

    for (int t0 = 0; t0 < TC; t0 += TT) {
        __syncthreads();               // protect tile from prior readers
        // stage TT x H floats: thread loads 8 float4, coalesced 4KB steps
#pragma unroll
        for (int k = 0; k < 8; k++) {
            *(float4*)(tile + 4 * tid + k * 1024) =
                *(const float4*)(encb + (size_t)t0 * H + 4 * tid + k * 1024);
        }
        __syncthreads();
        // scores: wave w computes rows 4w..4w+3 (stride-64 reads, 2-way=free)
#pragma unroll
        for (int r = 0; r < 4; r++) {
            int row = wave * 4 + r;
            const float* tr = tile + row * H;
            float d = 0.0f;
#pragma unroll
            for (int j = 0; j < 8; j++) d += we[j] * tr[lane + j * 64];
#pragma unroll
            for (int off = 32; off; off >>= 1) d += __shfl_xor(d, off);
            if (lane == 0) {
                s_tile[row] = d;
                score_out[b * T + c * TC + t0 + row] = d;
            }
        }
        __syncthreads();
        // online-softmax update (thread-redundant, deterministic)
        float s[TT], tmax = -1e30f;
#pragma unroll
        for (int i = 0; i < TT; i++) { s[i] = s_tile[i]; tmax = fmaxf(tmax, s[i]); }
        float m_new = fmaxf(m_run, tmax);
        float alpha = __expf(m_run - m_new);
        accx *= alpha; accy *= alpha;
        float wsum = 0.0f;
        // thread owns cols tid and tid+256 (bank = tid%32, 2-way = free)
#pragma unroll
        for (int i = 0; i < TT; i++) {
            float w = __expf(s[i] - m_new);
            wsum += w;
            accx += w * tile[i * H + tid];
            accy += w * tile[i * H + tid + 256];
        }
        l_run = l_run * alpha + wsum;
        m_run = m_new;
    }
    part[((size_t)c * B + b) * H + tid]       = accx;
    part[((size_t)c * B + b) * H + tid + 256] = accy;
    if (tid == 0) {
        stats[(c * B + b) * 2]     = m_run;
        stats[(c * B + b) * 2 + 1] = l_run;
    }
}

// ---------------------------------------------------------------------------
// Combine chunk partials -> attn_applied; emit normalized attn_weights.
// grid B x 256.
__global__ void attn_reduce_kernel(const float* __restrict__ part,
                                   const float* __restrict__ stats,
                                   const float* __restrict__ score,
                                   float* __restrict__ attn_applied,
                                   float* __restrict__ attnw) {
    int b = blockIdx.x, tid = threadIdx.x;
    float mc[C], lc[C], m_fin = -1e30f;
#pragma unroll
    for (int k = 0; k < C; k++) {
        mc[k] = stats[(k * B + b) * 2];
        lc[k] = stats[(k * B + b) * 2 + 1];
        m_fin = fmaxf(m_fin, mc[k]);
    }
    float l_fin = 0.0f;
#pragma unroll
    for (int k = 0; k < C; k++) l_fin += lc[k] * __expf(mc[k] - m_fin);
    float inv = 1.0f / l_fin;
    float ax = 0.0f, ay = 0.0f;
#pragma unroll
    for (int k = 0; k < C; k++) {
        float sc = __expf(mc[k] - m_fin);
        ax += sc * part[((size_t)k * B + b) * H + tid];
        ay += sc * part[((size_t)k * B + b) * H + tid + 256];
    }
    attn_applied[(size_t)b * H + tid]       = ax * inv;
    attn_applied[(size_t)b * H + tid + 256] = ay * inv;
    float4 sv = *(const float4*)(score + b * T + tid * 4);
    float4 ov = { __expf(sv.x - m_fin) * inv, __expf(sv.y - m_fin) * inv,
                  __expf(sv.z - m_fin) * inv, __expf(sv.w - m_fin) * inv };
    *(float4*)(attnw + b * T + tid * 4) = ov;
}

// ---------------------------------------------------------------------------
// x[b,h] = relu(in0[b]*comb_w[h,0] + attn[b,:]·comb_w[h,1:] + comb_b[h])
// grid (4, B) x 256; wave-per-row dots.
__global__ void comb_kernel(const float* __restrict__ attn_applied,
                            const float* __restrict__ input,
                            const float* __restrict__ comb_w,
                            const float* __restrict__ comb_b,
                            float* __restrict__ x_out) {
    int q = blockIdx.x, b = blockIdx.y, tid = threadIdx.x;
    int lane = tid & 63, wave = tid >> 6;
    float in0 = input[b * 8 + 7];     // input[:, -1], block-uniform
    float areg[8];
#pragma unroll
    for (int j = 0; j < 8; j++) areg[j] = attn_applied[(size_t)b * H + j * 64 + lane];
    for (int r = 0; r < 32; r++) {
        int h = q * 128 + wave * 32 + r;
        const float* wr = comb_w + (size_t)h * (H + 1);
        float d = 0.0f;
#pragma unroll
        for (int j = 0; j < 8; j++) d += areg[j] * wr[1 + j * 64 + lane];
#pragma unroll
        for (int off = 32; off; off >>= 1) d += __shfl_xor(d, off);
        if (lane == 0)
            x_out[(size_t)b * H + h] = fmaxf(0.0f, d + in0 * wr[0] + comb_b[h]);
    }
}

// ---------------------------------------------------------------------------
// C = A @ W^T, split-K. A:(B x H), W:(3H x H), C-partials:(KS x B x 3H).
// grid (48, 4, 2*KS): z = ks*2 + sel, sel picks (x,w_ih,gx) vs (hidden,w_hh,gh).
__global__ void gemm_kernel(const float* __restrict__ A0,
                            const float* __restrict__ A1,
                            const float* __restrict__ W0,
                            const float* __restrict__ W1,
                            float* __restrict__ C0,
                            float* __restrict__ C1) {
    int z = blockIdx.z;
    int sel = z & 1, ks = z >> 1;
    const float* A = sel ? A1 : A0;
    const float* W = sel ? W1 : W0;
    float* Cp = (sel ? C1 : C0) + (size_t)ks * B * G3H;
    __shared__ float As[32][33];
    __shared__ float Ws[32][33];
    int n0 = blockIdx.x * 32, m0 = blockIdx.y * 32;
    int tid = threadIdx.x;
    int lrow = tid >> 3;            // 0..31
    int lcol = (tid & 7) * 4;       // 0,4,..,28
    int tm = (tid >> 4) * 2;        // 0..30 even
    int tn = (tid & 15) * 2;
    float a00 = 0, a01 = 0, a10 = 0, a11 = 0;
    int kbeg = ks * (H / KS), kend = kbeg + H / KS;
    for (int k0 = kbeg; k0 < kend; k0 += 32) {
        float4 av = *(const float4*)(A + (size_t)(m0 + lrow) * H + k0 + lcol);
        float4 wv = *(const float4*)(W + (size_t)(n0 + lrow) * H + k0 + lcol);
        __syncthreads();
        As[lrow][lcol] = av.x; As[lrow][lcol + 1] = av.y;
        As[lrow][lcol + 2] = av.z; As[lrow][lcol + 3] = av.w;
        Ws[lrow][lcol] = wv.x; Ws[lrow][lcol + 1] = wv.y;
        Ws[lrow][lcol + 2] = wv.z; Ws[lrow][lcol + 3] = wv.w;
        __syncthreads();
#pragma unroll
        for (int k = 0; k < 32; k++) {
            float x0 = As[tm][k], x1 = As[tm + 1][k];
            float w0 = Ws[tn][k], w1 = Ws[tn + 1][k];
            a00 += x0 * w0; a01 += x0 * w1;
            a10 += x1 * w0; a11 += x1 * w1;
        }
    }
    Cp[(size_t)(m0 + tm) * G3H + n0 + tn]         = a00;
    Cp[(size_t)(m0 + tm) * G3H + n0 + tn + 1]     = a01;
    Cp[(size_t)(m0 + tm + 1) * G3H + n0 + tn]     = a10;
    Cp[(size_t)(m0 + tm + 1) * G3H + n0 + tn + 1] = a11;
}

// ---------------------------------------------------------------------------
// GRU gate combine; sums KS split-K partials. grid 256 x 256.
__global__ void gates_kernel(const float* __restrict__ gx,
                             const float* __restrict__ gh,
                             const float* __restrict__ b_ih,
                             const float* __restrict__ b_hh,
                             const float* __restrict__ hprev,
                             float* __restrict__ hid_out,
                             float* __restrict__ x_out) {
    int idx = blockIdx.x * 256 + threadIdx.x;   // 0..65535
    int b = idx >> 9, h = idx & 511;
    size_t gb = (size_t)b * G3H;
    float xr = b_ih[h], xz = b_ih[H + h], xn = b_ih[2 * H + h];
    float hr = b_hh[h], hz = b_hh[H + h], hn = b_hh[2 * H + h];
#pragma unroll
    for (int k = 0; k < KS; k++) {
        size_t o = (size_t)k * B * G3H + gb;
        xr += gx[o + h];         xz += gx[o + H + h];     xn += gx[o + 2 * H + h];
        hr += gh[o + h];         hz += gh[o + H + h];     hn += gh[o + 2 * H + h];
    }
    float hp = hprev[(size_t)b * H + h];
    float r = 1.0f / (1.0f + expf(-(xr + hr)));
    float z = 1.0f / (1.0f + expf(-(xz + hz)));
    float n = tanhf(xn + r * hn);
    float hnew = (1.0f - z) * n + z * hp;
    hid_out[(size_t)b * H + h] = hnew;
    x_out[(size_t)b * H + h] = hnew;
}

// ---------------------------------------------------------------------------
// output[b] = dot(x[b], out_w) + out_b. grid B x 64.
__global__ void out_kernel(const float* __restrict__ x,
                           const float* __restrict__ out_w,
                           const float* __restrict__ out_b,
                           float* __restrict__ out) {
    int b = blockIdx.x, lane = threadIdx.x;
    const float4 w0 = *(const float4*)(out_w + lane * 8);
    const float4 w1 = *(const float4*)(out_w + lane * 8 + 4);
    const float4 x0 = *(const float4*)(x + (size_t)b * H + lane * 8);
    const float4 x1 = *(const float4*)(x + (size_t)b * H + lane * 8 + 4);
    float d = x0.x * w0.x + x0.y * w0.y + x0.z * w0.z + x0.w * w0.w
            + x1.x * w1.x + x1.y * w1.y + x1.z * w1.z + x1.w * w1.w;
#pragma unroll
    for (int off = 32; off; off >>= 1) d += __shfl_xor(d, off);
    if (lane == 0) out[b] = d + out_b[0];
}

// ---------------------------------------------------------------------------
extern "C" void kernel_launch(void* const* d_in, const int* in_sizes, int n_in,
                              void* d_out, int out_size, void* d_ws, size_t ws_size,
                              hipStream_t stream) {
    const float* input  = (const float*)d_in[0];
    const float* hidden = (const float*)d_in[1];
    const float* enc    = (const float*)d_in[2];
    const float* attn_w = (const float*)d_in[3];
    // d_in[4] = attn_b: cancels under softmax
    const float* comb_w = (const float*)d_in[5];
    const float* comb_b = (const float*)d_in[6];
    const float* w_ih   = (const float*)d_in[7];
    const float* w_hh   = (const float*)d_in[8];
    const float* b_ih   = (const float*)d_in[9];
    const float* b_hh   = (const float*)d_in[10];
    const float* out_w  = (const float*)d_in[11];
    const float* out_b  = (const float*)d_in[12];

    float* out = (float*)d_out;
    // d_out layout: output[128] | hidden_out[L*B*H] | attn_weights[B*T]
    float* hid_out = out + B;
    float* attnw   = out + B + L * B * H;

    float* ws      = (float*)d_ws;
    float* score   = ws;                       // B*T          = 131072
    float* part    = score + B * T;            // C*B*H        = 524288
    float* stats   = part + C * B * H;         // C*B*2        = 2048
    float* attnapp = stats + C * B * 2;        // B*H          = 65536
    float* x       = attnapp + B * H;          // B*H          = 65536
    float* gx      = x + B * H;                // KS*B*3H      = 786432
    float* gh      = gx + KS * B * G3H;        // KS*B*3H      = 786432

    attn_fused_kernel<<<dim3(C, B), 256, 0, stream>>>(enc, attn_w, score, part, stats);
    attn_reduce_kernel<<<dim3(B), 256, 0, stream>>>(part, stats, score, attnapp, attnw);
    comb_kernel<<<dim3(4, B), 256, 0, stream>>>(attnapp, input, comb_w, comb_b, x);

    for (int l = 0; l < L; l++) {
        const float* hl = hidden + (size_t)l * B * H;
        gemm_kernel<<<dim3(G3H / 32, B / 32, 2 * KS), 256, 0, stream>>>(
            x, hl,
            w_ih + (size_t)l * G3H * H, w_hh + (size_t)l * G3H * H,
            gx, gh);
        gates_kernel<<<dim3(B * H / 256), 256, 0, stream>>>(
            gx, gh, b_ih + l * G3H, b_hh + l * G3H, hl,
            hid_out + (size_t)l * B * H, x);
    }
    out_kernel<<<dim3(B), 64, 0, stream>>>(x, out_w, out_b, out);
}